// Round 3
// baseline (1037.144 us; speedup 1.0000x reference)
//
#include <hip/hip_runtime.h>

// GHMC loss, round 3: direct binning + lane-private LDS scatter.
//   loss = sum_b (S_b / C_b) / n_nonempty,  b in 0..9,  (tot cancels)
// Per element: g = |x-t|, bin idx = min((int)(g*10), 9), discarded (slot 10)
// if g >= 1+1e-6.  Accumulate S and C with one ds_add_f32 each into a
// lane-private LDS region (stride 11 floats: coprime with 32 banks -> <=2-way
// conflicts, which are free; thread-private -> no contention, DS ops in-order
// per wave so no sync needed).  Counts in f32 are exact (<= 2^24 per lane).
// This replaces the ~30-op per-slot cndmask chain of rounds 1-2 with
// ~5 VALU ops + 2 DS ops per element -> instruction-issue cost ~3x lower.

#define NBINS 11    // 10 real bins + discard slot
#define LSTRIDE 11  // lane-private region stride
#define THREADS 256

__device__ __forceinline__ float bce(float x, float t) {
    // max(x,0) - x*t + log1p(exp(-|x|)); hw v_exp/v_log ~2ulp, negligible
    return fmaxf(x, 0.0f) - x * t + __logf(1.0f + __expf(-fabsf(x)));
}

__global__ __launch_bounds__(THREADS) void ghmc_partial(
    const float4* __restrict__ p4, const float4* __restrict__ t4, int n4,
    const float* __restrict__ p1, const float* __restrict__ t1, long long ntot,
    double* __restrict__ g_sum, unsigned int* __restrict__ g_cnt) {

    __shared__ float lds_sum[THREADS * LSTRIDE];
    __shared__ float lds_cnt[THREADS * LSTRIDE];

    const int tid = threadIdx.x;
    float* mysum = &lds_sum[tid * LSTRIDE];
    float* mycnt = &lds_cnt[tid * LSTRIDE];
#pragma unroll
    for (int b = 0; b < NBINS; ++b) { mysum[b] = 0.0f; mycnt[b] = 0.0f; }
    // no __syncthreads: regions are thread-private; DS ops in-order per wave

    const float EDGE10 = 1.0f + 1e-6f;  // == f32(edges[-1]) in the reference

    auto put = [&](float x, float t) {
        const float g = fabsf(x - t);
        const float l = bce(x, t);
        int idx = (int)(g * 10.0f);          // v_mul + v_cvt (trunc)
        idx = (idx > 9) ? 9 : idx;           // g in [1.0, 1+1e-6) -> bin 9
        idx = (g >= EDGE10) ? 10 : idx;      // out-of-range -> discard slot
        atomicAdd(&mysum[idx], l);           // ds_add_f32, lane-private
        atomicAdd(&mycnt[idx], 1.0f);        // ds_add_f32 (exact: cnt < 2^24)
    };

    const int stride = gridDim.x * blockDim.x;
    for (int i = blockIdx.x * blockDim.x + tid; i < n4; i += stride) {
        const float4 p = p4[i];
        const float4 t = t4[i];
        put(p.x, t.x); put(p.y, t.y); put(p.z, t.z); put(p.w, t.w);
    }
    // scalar tail for ntot % 4 (never taken for this shape)
    if (blockIdx.x == 0 && tid == 0) {
        for (long long j = (long long)n4 * 4; j < ntot; ++j) put(p1[j], t1[j]);
    }

    // read back own bins; 64-lane tree reduce; block reduce; global atomics
    float s[NBINS], c[NBINS];
#pragma unroll
    for (int b = 0; b < NBINS; ++b) { s[b] = mysum[b]; c[b] = mycnt[b]; }
#pragma unroll
    for (int off = 32; off > 0; off >>= 1) {
#pragma unroll
        for (int b = 0; b < NBINS; ++b) {
            s[b] += __shfl_down(s[b], off, 64);
            c[b] += __shfl_down(c[b], off, 64);
        }
    }

    __shared__ float w_sum[4][NBINS];
    __shared__ float w_cnt[4][NBINS];
    const int wave = tid >> 6;
    const int lane = tid & 63;
    if (lane == 0) {
#pragma unroll
        for (int b = 0; b < NBINS; ++b) { w_sum[wave][b] = s[b]; w_cnt[wave][b] = c[b]; }
    }
    __syncthreads();
    if (tid < NBINS) {
        const float fs = w_sum[0][tid] + w_sum[1][tid] + w_sum[2][tid] + w_sum[3][tid];
        const float fc = w_cnt[0][tid] + w_cnt[1][tid] + w_cnt[2][tid] + w_cnt[3][tid];
        atomicAdd(&g_sum[tid], (double)fs);
        atomicAdd(&g_cnt[tid], (unsigned int)(fc + 0.5f));  // exact integer in f32
    }
}

__global__ void ghmc_final(const double* __restrict__ g_sum,
                           const unsigned int* __restrict__ g_cnt,
                           float* __restrict__ out) {
    if (blockIdx.x == 0 && threadIdx.x == 0) {
        double loss = 0.0;
        int n = 0;
#pragma unroll
        for (int b = 0; b < 10; ++b) {  // slot 10 (out-of-range) ignored
            const unsigned c = g_cnt[b];
            if (c > 0u) {
                n += 1;
                loss += g_sum[b] / (double)c;
            }
        }
        loss /= (n > 0) ? (double)n : 1.0;
        out[0] = (float)loss;
    }
}

extern "C" void kernel_launch(void* const* d_in, const int* in_sizes, int n_in,
                              void* d_out, int out_size, void* d_ws, size_t ws_size,
                              hipStream_t stream) {
    const float* pred = (const float*)d_in[0];
    const float* tgt  = (const float*)d_in[1];
    long long ntot = (long long)in_sizes[0];
    int n4 = (int)(ntot / 4);

    double* g_sum = (double*)d_ws;                                   // 11 doubles
    unsigned int* g_cnt = (unsigned int*)((char*)d_ws + NBINS * sizeof(double));

    hipMemsetAsync(d_ws, 0, NBINS * sizeof(double) + NBINS * sizeof(unsigned int),
                   stream);

    const int threads = THREADS;
    const int blocks = 2048;  // 8 blocks/CU target; grid-stride, 32 float4/thread
    hipLaunchKernelGGL(ghmc_partial, dim3(blocks), dim3(threads), 0, stream,
                       (const float4*)pred, (const float4*)tgt, n4,
                       pred, tgt, ntot, g_sum, g_cnt);
    hipLaunchKernelGGL(ghmc_final, dim3(1), dim3(64), 0, stream,
                       g_sum, g_cnt, (float*)d_out);
}

// Round 4
// 545.060 us; speedup vs baseline: 1.9028x; 1.9028x over previous
//
#include <hip/hip_runtime.h>

// GHMC loss, round 4: direct binning, lane-private NON-ATOMIC LDS RMW for
// per-bin loss sums, and register-packed 6-bit counters for bin counts.
//   loss = sum_b (S_b / C_b) / n_nonempty,  b in 0..9   (tot cancels)
// Round-3 lesson: scattered LDS *atomics* cost ~50 CU-cyc/wave-op. Plain
// ds_read+v_add+ds_write to thread-private slots is ~6 cyc/op (in-order LDS
// pipe per wave guarantees the RMW chain is correct without sync).
// Counts never touch memory: c += 1ull << (6*idx) packs 10 six-bit fields in
// a u64; invalid elements (g >= 1+1e-6) go to idx=10 -> bits 60..63, which
// are never read (carry-out of bit 63 is silently dropped). Two alternating
// accumulators cap any field at 32 (<63) for the 16-iter main loop.

#define THREADS 256
#define LSTRIDE 11   // 10 bins + discard slot per thread
#define NB 10

__device__ __forceinline__ float bce(float x, float t) {
    // max(x,0) - x*t + log1p(exp(-|x|)); hw v_exp/v_log ~2ulp, negligible
    return fmaxf(x, 0.0f) - x * t + __logf(1.0f + __expf(-fabsf(x)));
}

__global__ __launch_bounds__(THREADS) void ghmc_partial(
    const float4* __restrict__ p4, const float4* __restrict__ t4, int n4,
    const float* __restrict__ p1, const float* __restrict__ t1, long long ntot,
    double* __restrict__ g_sum, unsigned int* __restrict__ g_cnt) {

    __shared__ float lds[THREADS * LSTRIDE];
    const int tid = threadIdx.x;
    float* slots = &lds[tid * LSTRIDE];  // stride 11: coprime w/ 32 banks
#pragma unroll
    for (int b = 0; b < LSTRIDE; ++b) slots[b] = 0.0f;
    // no barrier: regions are thread-private; LDS pipe is in-order per wave

    const float EDGE10 = 1.0f + 1e-6f;   // f32(edges[-1]) in the reference
    unsigned long long ca = 0ull, cb = 0ull;
    unsigned cnt[NB];
#pragma unroll
    for (int b = 0; b < NB; ++b) cnt[b] = 0u;

    // trunc(g*10) matches searchsorted on the f32 edge grid exactly
    // (hand-checked rounding at 0.1f,0.2f,0.3f,0.7f,0.9f,1.0 boundaries);
    // g in [1.0, 1+1e-6) -> idx 10 -> clamped to 9 (= reference bin 9).
    auto put = [&](float x, float t, unsigned long long& c) {
        const float g = fabsf(x - t);
        const float l = bce(x, t);
        int idx = (int)(g * 10.0f);
        idx = idx > 9 ? 9 : idx;
        idx = (g < EDGE10) ? idx : 10;   // out-of-range -> discard slot
        c += 1ull << (6 * idx);          // packed 6-bit per-bin count
        slots[idx] += l;                 // ds_read + v_add + ds_write
    };
    auto flushc = [&](unsigned long long& c) {
#pragma unroll
        for (int b = 0; b < NB; ++b) cnt[b] += (unsigned)((c >> (6 * b)) & 63ull);
        c = 0ull;
    };

    const int stride = gridDim.x * blockDim.x;
    int i = blockIdx.x * blockDim.x + tid;
    const int iters = n4 / stride;       // 16 for this shape -> <=32/field

    float4 p, t;
    if (iters > 0) { p = p4[i]; t = t4[i]; }
    for (int it = 0; it < iters; ++it) {
        const int inext = i + stride;
        float4 pn, tn;
        if (it + 1 < iters) { pn = p4[inext]; tn = t4[inext]; }  // prefetch
        put(p.x, t.x, ca); put(p.y, t.y, cb);
        put(p.z, t.z, ca); put(p.w, t.w, cb);
        p = pn; t = tn; i = inext;
    }
    flushc(ca); flushc(cb);

    // grid-stride remainder (not taken for this shape); flush every iter
    for (; i < n4; i += stride) {
        const float4 pp = p4[i], tt = t4[i];
        put(pp.x, tt.x, ca); put(pp.y, tt.y, cb);
        put(pp.z, tt.z, ca); put(pp.w, tt.w, cb);
        flushc(ca); flushc(cb);
    }
    // scalar tail for ntot % 4 (not taken here): direct global atomics
    if (blockIdx.x == 0 && tid == 0) {
        for (long long j = (long long)n4 * 4; j < ntot; ++j) {
            const float x = p1[j], tt = t1[j];
            const float g = fabsf(x - tt);
            if (g < EDGE10) {
                int idx = (int)(g * 10.0f);
                idx = idx > 9 ? 9 : idx;
                atomicAdd(&g_sum[idx], (double)bce(x, tt));
                atomicAdd(&g_cnt[idx], 1u);
            }
        }
    }

    // read back own bins (in-order LDS pipe; compiler inserts lgkm waits)
    float s[NB];
#pragma unroll
    for (int b = 0; b < NB; ++b) s[b] = slots[b];

#pragma unroll
    for (int off = 32; off > 0; off >>= 1) {
#pragma unroll
        for (int b = 0; b < NB; ++b) {
            s[b] += __shfl_down(s[b], off, 64);
            cnt[b] += __shfl_down(cnt[b], off, 64);
        }
    }

    __shared__ float w_sum[4][NB];
    __shared__ unsigned w_cnt[4][NB];
    const int wave = tid >> 6;
    const int lane = tid & 63;
    if (lane == 0) {
#pragma unroll
        for (int b = 0; b < NB; ++b) { w_sum[wave][b] = s[b]; w_cnt[wave][b] = cnt[b]; }
    }
    __syncthreads();
    if (tid < NB) {
        const float fs = w_sum[0][tid] + w_sum[1][tid] + w_sum[2][tid] + w_sum[3][tid];
        const unsigned fc = w_cnt[0][tid] + w_cnt[1][tid] + w_cnt[2][tid] + w_cnt[3][tid];
        atomicAdd(&g_sum[tid], (double)fs);
        atomicAdd(&g_cnt[tid], fc);
    }
}

__global__ void ghmc_final(const double* __restrict__ g_sum,
                           const unsigned int* __restrict__ g_cnt,
                           float* __restrict__ out) {
    if (blockIdx.x == 0 && threadIdx.x == 0) {
        double loss = 0.0;
        int n = 0;
#pragma unroll
        for (int b = 0; b < NB; ++b) {
            const unsigned c = g_cnt[b];
            if (c > 0u) {
                n += 1;
                loss += g_sum[b] / (double)c;
            }
        }
        loss /= (n > 0) ? (double)n : 1.0;
        out[0] = (float)loss;
    }
}

extern "C" void kernel_launch(void* const* d_in, const int* in_sizes, int n_in,
                              void* d_out, int out_size, void* d_ws, size_t ws_size,
                              hipStream_t stream) {
    const float* pred = (const float*)d_in[0];
    const float* tgt  = (const float*)d_in[1];
    long long ntot = (long long)in_sizes[0];
    int n4 = (int)(ntot / 4);

    double* g_sum = (double*)d_ws;                                  // 10 doubles
    unsigned int* g_cnt = (unsigned int*)((char*)d_ws + NB * sizeof(double));

    hipMemsetAsync(d_ws, 0, NB * sizeof(double) + NB * sizeof(unsigned int),
                   stream);

    const int threads = THREADS;
    const int blocks = 4096;  // stride 1,048,576 -> exactly 16 float4/thread
    hipLaunchKernelGGL(ghmc_partial, dim3(blocks), dim3(threads), 0, stream,
                       (const float4*)pred, (const float4*)tgt, n4,
                       pred, tgt, ntot, g_sum, g_cnt);
    hipLaunchKernelGGL(ghmc_final, dim3(1), dim3(64), 0, stream,
                       g_sum, g_cnt, (float*)d_out);
}

// Round 5
// 519.927 us; speedup vs baseline: 1.9948x; 1.0483x over previous
//
#include <hip/hip_runtime.h>

// GHMC loss, round 5: r4 compute core (direct binning, lane-private
// non-atomic LDS RMW sums, register-packed 6-bit counts) + memory
// restructure: block-contiguous chunks (DRAM row locality) and prefetch
// depth 4 (8 KB in flight per wave, 4x round 4's MLP).
//   loss = sum_b (S_b / C_b) / n_nonempty   (tot cancels algebraically)

#define THREADS 256
#define LSTRIDE 11   // 10 bins + discard slot per thread
#define NB 10
#define PF 4         // prefetch group: 4 float4-pairs in flight

__device__ __forceinline__ float bce(float x, float t) {
    // max(x,0) - x*t + log1p(exp(-|x|)); hw v_exp/v_log ~2ulp, negligible
    return fmaxf(x, 0.0f) - x * t + __logf(1.0f + __expf(-fabsf(x)));
}

__global__ __launch_bounds__(THREADS) void ghmc_partial(
    const float4* __restrict__ p4, const float4* __restrict__ t4, int n4,
    const float* __restrict__ p1, const float* __restrict__ t1, long long ntot,
    double* __restrict__ g_sum, unsigned int* __restrict__ g_cnt) {

    __shared__ float lds[THREADS * LSTRIDE];
    const int tid = threadIdx.x;
    float* slots = &lds[tid * LSTRIDE];  // stride 11: <=2-way bank alias, free
#pragma unroll
    for (int b = 0; b < LSTRIDE; ++b) slots[b] = 0.0f;
    // no barrier: regions thread-private; LDS pipe in-order per wave

    const float EDGE10 = 1.0f + 1e-6f;   // f32(edges[-1]) in the reference
    // 4 packed counters (one per float4 component): 10 six-bit fields each;
    // invalid elems go to bits 60..63 (never read). Max increments per
    // accumulator between flushes: 15 groups * PF = 60 < 63.
    unsigned long long cc[4] = {0ull, 0ull, 0ull, 0ull};
    unsigned cnt[NB];
#pragma unroll
    for (int b = 0; b < NB; ++b) cnt[b] = 0u;

    // trunc(g*10) matches f32 searchsorted edges exactly (verified r3/r4,
    // absmax 0); g in [1.0,1+1e-6) -> idx 10 -> clamp 9 = reference bin 9.
    auto put = [&](float x, float t, unsigned long long& c) {
        const float g = fabsf(x - t);
        const float l = bce(x, t);
        int idx = (int)(g * 10.0f);
        idx = idx > 9 ? 9 : idx;
        idx = (g < EDGE10) ? idx : 10;
        c += 1ull << (6 * idx);
        slots[idx] += l;                 // ds_read + v_add + ds_write
    };
    auto flush_all = [&]() {
#pragma unroll
        for (int q = 0; q < 4; ++q) {
#pragma unroll
            for (int b = 0; b < NB; ++b)
                cnt[b] += (unsigned)((cc[q] >> (6 * b)) & 63ull);
            cc[q] = 0ull;
        }
    };

    // ---- block-contiguous partitioning ----
    const int chunk = (n4 + (int)gridDim.x - 1) / (int)gridDim.x;
    const int start = blockIdx.x * chunk;
    const int end = min(start + chunk, n4);
    const int count = max(end - start, 0);
    const int full = count / THREADS;        // full block-strided iters (32)
    const int ngrp = full / PF;              // prefetch groups (8)

    float4 P[PF], T[PF], Pn[PF], Tn[PF];
    if (ngrp > 0) {
#pragma unroll
        for (int g = 0; g < PF; ++g) {
            const int id = start + g * THREADS + tid;
            P[g] = p4[id]; T[g] = t4[id];
        }
    }
    for (int g2 = 0; g2 < ngrp; ++g2) {
        const int nb = start + (g2 + 1) * PF * THREADS + tid;
        if (g2 + 1 < ngrp) {
#pragma unroll
            for (int g = 0; g < PF; ++g) {
                Pn[g] = p4[nb + g * THREADS];
                Tn[g] = t4[nb + g * THREADS];
            }
        }
#pragma unroll
        for (int g = 0; g < PF; ++g) {
            put(P[g].x, T[g].x, cc[0]);
            put(P[g].y, T[g].y, cc[1]);
            put(P[g].z, T[g].z, cc[2]);
            put(P[g].w, T[g].w, cc[3]);
        }
        if ((g2 % 15) == 14) flush_all();    // never taken at ngrp=8; generic
#pragma unroll
        for (int g = 0; g < PF; ++g) { P[g] = Pn[g]; T[g] = Tn[g]; }
    }
    // leftover full iters (full % PF) — not taken for this shape
    for (int k = ngrp * PF; k < full; ++k) {
        const int id = start + k * THREADS + tid;
        const float4 pp = p4[id], tt = t4[id];
        put(pp.x, tt.x, cc[0]); put(pp.y, tt.y, cc[1]);
        put(pp.z, tt.z, cc[2]); put(pp.w, tt.w, cc[3]);
    }
    // tail float4s within the chunk — not taken for this shape
    {
        const int id = start + full * THREADS + tid;
        if (id < end) {
            const float4 pp = p4[id], tt = t4[id];
            put(pp.x, tt.x, cc[0]); put(pp.y, tt.y, cc[1]);
            put(pp.z, tt.z, cc[2]); put(pp.w, tt.w, cc[3]);
        }
    }
    flush_all();

    // scalar tail for ntot % 4 (not taken here): direct global atomics
    if (blockIdx.x == 0 && tid == 0) {
        for (long long j = (long long)n4 * 4; j < ntot; ++j) {
            const float x = p1[j], tt = t1[j];
            const float g = fabsf(x - tt);
            if (g < EDGE10) {
                int idx = (int)(g * 10.0f);
                idx = idx > 9 ? 9 : idx;
                atomicAdd(&g_sum[idx], (double)bce(x, tt));
                atomicAdd(&g_cnt[idx], 1u);
            }
        }
    }

    // read back own bins; 64-lane tree reduce; block reduce; global atomics
    float s[NB];
#pragma unroll
    for (int b = 0; b < NB; ++b) s[b] = slots[b];
#pragma unroll
    for (int off = 32; off > 0; off >>= 1) {
#pragma unroll
        for (int b = 0; b < NB; ++b) {
            s[b] += __shfl_down(s[b], off, 64);
            cnt[b] += __shfl_down(cnt[b], off, 64);
        }
    }

    __shared__ float w_sum[4][NB];
    __shared__ unsigned w_cnt[4][NB];
    const int wave = tid >> 6;
    const int lane = tid & 63;
    if (lane == 0) {
#pragma unroll
        for (int b = 0; b < NB; ++b) { w_sum[wave][b] = s[b]; w_cnt[wave][b] = cnt[b]; }
    }
    __syncthreads();
    if (tid < NB) {
        const float fs = w_sum[0][tid] + w_sum[1][tid] + w_sum[2][tid] + w_sum[3][tid];
        const unsigned fc = w_cnt[0][tid] + w_cnt[1][tid] + w_cnt[2][tid] + w_cnt[3][tid];
        atomicAdd(&g_sum[tid], (double)fs);
        atomicAdd(&g_cnt[tid], fc);
    }
}

__global__ void ghmc_final(const double* __restrict__ g_sum,
                           const unsigned int* __restrict__ g_cnt,
                           float* __restrict__ out) {
    if (blockIdx.x == 0 && threadIdx.x == 0) {
        double loss = 0.0;
        int n = 0;
#pragma unroll
        for (int b = 0; b < NB; ++b) {
            const unsigned c = g_cnt[b];
            if (c > 0u) {
                n += 1;
                loss += g_sum[b] / (double)c;
            }
        }
        loss /= (n > 0) ? (double)n : 1.0;
        out[0] = (float)loss;
    }
}

extern "C" void kernel_launch(void* const* d_in, const int* in_sizes, int n_in,
                              void* d_out, int out_size, void* d_ws, size_t ws_size,
                              hipStream_t stream) {
    const float* pred = (const float*)d_in[0];
    const float* tgt  = (const float*)d_in[1];
    long long ntot = (long long)in_sizes[0];
    int n4 = (int)(ntot / 4);

    double* g_sum = (double*)d_ws;                                  // 10 doubles
    unsigned int* g_cnt = (unsigned int*)((char*)d_ws + NB * sizeof(double));

    hipMemsetAsync(d_ws, 0, NB * sizeof(double) + NB * sizeof(unsigned int),
                   stream);

    const int threads = THREADS;
    const int blocks = 2048;  // chunk = 8192 float4/block = 128 KB window
    hipLaunchKernelGGL(ghmc_partial, dim3(blocks), dim3(threads), 0, stream,
                       (const float4*)pred, (const float4*)tgt, n4,
                       pred, tgt, ntot, g_sum, g_cnt);
    hipLaunchKernelGGL(ghmc_final, dim3(1), dim3(64), 0, stream,
                       g_sum, g_cnt, (float*)d_out);
}